// Round 1
// baseline (464.059 us; speedup 1.0000x reference)
//
#include <hip/hip_runtime.h>

typedef __bf16 bf16;
typedef __bf16 bf16x8 __attribute__((ext_vector_type(8)));
typedef float f32x4 __attribute__((ext_vector_type(4)));

#define MFMA_BF16(a, b, c) __builtin_amdgcn_mfma_f32_16x16x32_bf16(a, b, c, 0, 0, 0)

__device__ __forceinline__ void async16(const void* g, void* l) {
    __builtin_amdgcn_global_load_lds(
        (const __attribute__((address_space(1))) void*)g,
        (__attribute__((address_space(3))) void*)l,
        16, 0, 0);
}

// ---------------- fp32 -> bf16 convert, 8 elems/thread ----------------
__global__ void cvt8(const float* __restrict__ in, bf16* __restrict__ out, int n) {
    int i = (blockIdx.x * 256 + threadIdx.x) * 8;
    if (i >= n) return;
    float4 a = *(const float4*)(in + i);
    float4 b = *(const float4*)(in + i + 4);
    bf16x8 o;
    o[0] = (bf16)a.x; o[1] = (bf16)a.y; o[2] = (bf16)a.z; o[3] = (bf16)a.w;
    o[4] = (bf16)b.x; o[5] = (bf16)b.y; o[6] = (bf16)b.z; o[7] = (bf16)b.w;
    *(bf16x8*)(out + i) = o;
}

// ---------------- RoPE tables (S=2048, hd=128) + key-mask bias ----------------
__global__ void tables_k(const int* __restrict__ am, float* __restrict__ cosT,
                         float* __restrict__ sinT, float* __restrict__ mbias) {
    int i = blockIdx.x * 256 + threadIdx.x;   // 0 .. 2048*128-1
    int s = i >> 7, d = i & 127, fi = d & 63;
    // inv_freq = 10000^(-fi/64) = exp2(-fi * log2(10000)/64)
    float inv = exp2f(-(float)fi * (13.287712379549449f / 64.0f));
    float ang = (float)s * inv;
    cosT[i] = cosf(ang);
    sinT[i] = sinf(ang);
    if (i < 2 * 2048) mbias[i] = (am[i] == 0) ? -1e30f : 0.0f;
}

// ---------------- GEMM: C[M,N] = A[M,K] @ Bt[N,K]^T + bias ----------------
// 128x128 tile, BK=64, 4 waves (2x2), each wave 64x64 via 4x4 of 16x16x32 MFMA.
// LDS xor-swizzled on 16B chunks: chunk x holds global chunk g = x ^ (row&7).
// EPI=0: fp32 store to Cf.  EPI=1: fused RoPE + scatter to q[bh,s,d], k[bh,s,d], vt[bh,d,s].
template <int EPI>
__global__ void __launch_bounds__(256, 2)
gemm_bt(const bf16* __restrict__ A, const bf16* __restrict__ Bt,
        const float* __restrict__ bias, float* __restrict__ Cf,
        bf16* __restrict__ qb, bf16* __restrict__ kb, bf16* __restrict__ vtb,
        const float* __restrict__ cosT, const float* __restrict__ sinT,
        int M, int N, int K) {
    __shared__ __align__(16) bf16 sA[128 * 64];
    __shared__ __align__(16) bf16 sB[128 * 64];
    const int tid  = threadIdx.x;
    const int lane = tid & 63;
    const int quad = lane >> 4, l15 = lane & 15;
    const int wid = tid >> 6, wm = wid >> 1, wn = wid & 1;
    const int bm = blockIdx.x, bn = blockIdx.y;

    f32x4 acc[4][4];
#pragma unroll
    for (int i = 0; i < 4; i++)
#pragma unroll
        for (int j = 0; j < 4; j++)
#pragma unroll
            for (int c = 0; c < 4; c++) acc[i][j][c] = 0.0f;

    // staging: 1024 chunks (16B) per 128x64 tile -> 4 insts x 256 threads
    const int r0 = tid >> 3, x0 = tid & 7;
    const int g0 = x0 ^ (r0 & 7);            // (r0+32i)&7 == r0&7
    const bf16* pa = A  + (size_t)(bm * 128 + r0) * K + g0 * 8;
    const bf16* pb = Bt + (size_t)(bn * 128 + r0) * K + g0 * 8;
    bf16* la = sA + tid * 8;
    bf16* lb = sB + tid * 8;
    const size_t gstep = (size_t)32 * K;

    for (int k0 = 0; k0 < K; k0 += 64) {
#pragma unroll
        for (int i = 0; i < 4; i++) {
            async16(pa + i * gstep, la + i * 2048);
            async16(pb + i * gstep, lb + i * 2048);
        }
        pa += 64; pb += 64;
        __syncthreads();
#pragma unroll
        for (int ks = 0; ks < 2; ks++) {
            bf16x8 af[4], bfr[4];
#pragma unroll
            for (int i = 0; i < 4; i++) {
                int r = wm * 64 + i * 16 + l15;
                int x = (ks * 4 + quad) ^ (r & 7);
                af[i] = *(const bf16x8*)(sA + r * 64 + x * 8);
            }
#pragma unroll
            for (int i = 0; i < 4; i++) {
                int r = wn * 64 + i * 16 + l15;
                int x = (ks * 4 + quad) ^ (r & 7);
                bfr[i] = *(const bf16x8*)(sB + r * 64 + x * 8);
            }
#pragma unroll
            for (int mi = 0; mi < 4; mi++)
#pragma unroll
                for (int ni = 0; ni < 4; ni++)
                    acc[mi][ni] = MFMA_BF16(af[mi], bfr[ni], acc[mi][ni]);
        }
        __syncthreads();
    }

    if (EPI == 0) {
#pragma unroll
        for (int mi = 0; mi < 4; mi++)
#pragma unroll
            for (int ni = 0; ni < 4; ni++) {
                int row0 = bm * 128 + wm * 64 + mi * 16 + quad * 4;
                int col  = bn * 128 + wn * 64 + ni * 16 + l15;
                float bv = bias[col];
#pragma unroll
                for (int r = 0; r < 4; r++)
                    Cf[(size_t)(row0 + r) * N + col] = acc[mi][ni][r] + bv;
            }
    } else {
        // QKV epilogue: col -> (which, head, d); row -> (b, s). RoPE on q,k.
#pragma unroll
        for (int mi = 0; mi < 4; mi++)
#pragma unroll
            for (int ni = 0; ni < 4; ni++) {
                int col   = bn * 128 + wn * 64 + ni * 16 + l15;
                int which = col >> 11;
                int hcol  = col & 2047;
                int h = hcol >> 7, d = hcol & 127;
                float bv = bias[col];
#pragma unroll
                for (int r = 0; r < 4; r++) {
                    int row = bm * 128 + wm * 64 + mi * 16 + quad * 4 + r;
                    int b = row >> 11, s = row & 2047;
                    float v  = acc[mi][ni][r] + bv;
                    float vp = __shfl_xor(v, 1, 64);   // partner column d^1
                    float ov = v;
                    if (which < 2) {
                        float c  = cosT[(s << 7) + d];
                        float sn = sinT[(s << 7) + d];
                        // out[2i] = v*cos - v[2i+1]*sin ; out[2i+1] = v*cos + v[2i]*sin
                        ov = v * c + ((d & 1) ? vp : -vp) * sn;
                    }
                    size_t bh = (size_t)(b * 16 + h);
                    if (which == 0)      qb[(bh * 2048 + s) * 128 + d] = (bf16)ov;
                    else if (which == 1) kb[(bh * 2048 + s) * 128 + d] = (bf16)ov;
                    else                 vtb[(bh * 128 + d) * 2048 + s] = (bf16)ov;
                }
            }
    }
}

// ---------------- Flash attention (causal), S=2048, hd=128, BM=128, BN=64 ----------------
// q [bh, s, d], k [bh, s, d], vt [bh, d, s]; out attn [b, s, h*128+d] bf16.
__global__ void __launch_bounds__(256, 2)
fattn(const bf16* __restrict__ Q, const bf16* __restrict__ Kg,
      const bf16* __restrict__ Vt, const float* __restrict__ mbias,
      bf16* __restrict__ O) {
    __shared__ __align__(16) bf16 sK[64 * 128];
    __shared__ __align__(16) bf16 sV[128 * 64];
    __shared__ __align__(16) bf16 sP[4 * 32 * 64];
    const int tid = threadIdx.x, lane = tid & 63, w = tid >> 6;
    const int quad = lane >> 4, l15 = lane & 15;
    const int qt = 15 - (int)blockIdx.x;      // heavy (late-diagonal) blocks first
    const int bh = blockIdx.y;
    const int b = bh >> 4, h = bh & 15;
    const int rowbase = qt * 128 + w * 32;

    const bf16* Qb  = Q  + (size_t)bh * 2048 * 128;
    const bf16* Kbh = Kg + (size_t)bh * 2048 * 128;
    const bf16* Vbh = Vt + (size_t)bh * 128 * 2048;
    const float* mbb = mbias + b * 2048;

    // resident Q fragments: 2 row-tiles x 4 k-steps
    bf16x8 qf[2][4];
#pragma unroll
    for (int mi = 0; mi < 2; mi++)
#pragma unroll
        for (int kq = 0; kq < 4; kq++)
            qf[mi][kq] = *(const bf16x8*)(Qb + (size_t)(rowbase + mi * 16 + l15) * 128 + kq * 32 + quad * 8);

    f32x4 oacc[2][8];
#pragma unroll
    for (int mi = 0; mi < 2; mi++)
#pragma unroll
        for (int ni = 0; ni < 8; ni++)
#pragma unroll
            for (int c = 0; c < 4; c++) oacc[mi][ni][c] = 0.0f;
    float m_s[2][4], l_s[2][4];
#pragma unroll
    for (int mi = 0; mi < 2; mi++)
#pragma unroll
        for (int r = 0; r < 4; r++) { m_s[mi][r] = -3e38f; l_s[mi][r] = 0.0f; }

    const int rk = tid >> 4, xk = tid & 15, gk = xk ^ (rk & 15);  // K tile: 16 chunks/row
    const int rv = tid >> 3, xv = tid & 7,  gv = xv ^ (rv & 7);   // V tile: 8 chunks/row
    const int nkt = (qt + 1) * 2;

    for (int kt = 0; kt < nkt; kt++) {
        const int kb0 = kt * 64;
#pragma unroll
        for (int i = 0; i < 4; i++) {
            async16(Kbh + (size_t)(kb0 + rk + i * 16) * 128 + gk * 8, sK + (i * 256 + tid) * 8);
            async16(Vbh + (size_t)(rv + i * 32) * 2048 + kb0 + gv * 8, sV + (i * 256 + tid) * 8);
        }
        __syncthreads();

        // S = Q K^T
        f32x4 sacc[2][4];
#pragma unroll
        for (int mi = 0; mi < 2; mi++)
#pragma unroll
            for (int nj = 0; nj < 4; nj++)
#pragma unroll
                for (int c = 0; c < 4; c++) sacc[mi][nj][c] = 0.0f;
#pragma unroll
        for (int kq = 0; kq < 4; kq++) {
            bf16x8 kf[4];
#pragma unroll
            for (int nj = 0; nj < 4; nj++) {
                int r = nj * 16 + l15;
                int x = (kq * 4 + quad) ^ (r & 15);
                kf[nj] = *(const bf16x8*)(sK + r * 128 + x * 8);
            }
#pragma unroll
            for (int mi = 0; mi < 2; mi++)
#pragma unroll
                for (int nj = 0; nj < 4; nj++)
                    sacc[mi][nj] = MFMA_BF16(qf[mi][kq], kf[nj], sacc[mi][nj]);
        }

        // scale + causal/key mask
        float pv[2][4][4];
#pragma unroll
        for (int mi = 0; mi < 2; mi++)
#pragma unroll
            for (int nj = 0; nj < 4; nj++) {
                int sk = kb0 + nj * 16 + l15;
                float mbv = mbb[sk];
#pragma unroll
                for (int r = 0; r < 4; r++) {
                    int sq = rowbase + mi * 16 + quad * 4 + r;
                    float val = sacc[mi][nj][r] * 0.08838834764831845f + mbv;
                    pv[mi][nj][r] = (sk > sq) ? -1e30f : val;
                }
            }

        // online softmax per row (row shared by the 16 lanes of a quad)
#pragma unroll
        for (int mi = 0; mi < 2; mi++)
#pragma unroll
            for (int r = 0; r < 4; r++) {
                float mx = fmaxf(fmaxf(pv[mi][0][r], pv[mi][1][r]),
                                 fmaxf(pv[mi][2][r], pv[mi][3][r]));
#pragma unroll
                for (int off = 1; off <= 8; off <<= 1)
                    mx = fmaxf(mx, __shfl_xor(mx, off, 64));
                float mnew  = fmaxf(m_s[mi][r], mx);
                float alpha = __expf(m_s[mi][r] - mnew);
                float rs = 0.0f;
#pragma unroll
                for (int nj = 0; nj < 4; nj++) {
                    float p = __expf(pv[mi][nj][r] - mnew);
                    pv[mi][nj][r] = p;
                    rs += p;
                }
#pragma unroll
                for (int off = 1; off <= 8; off <<= 1)
                    rs += __shfl_xor(rs, off, 64);
                l_s[mi][r] = l_s[mi][r] * alpha + rs;
                m_s[mi][r] = mnew;
#pragma unroll
                for (int ni = 0; ni < 8; ni++) oacc[mi][ni][r] *= alpha;
                // write P (bf16) to per-wave LDS, swizzled rows of 8 chunks
                int prow = mi * 16 + quad * 4 + r;
#pragma unroll
                for (int nj = 0; nj < 4; nj++) {
                    int col = nj * 16 + l15;
                    int x = (col >> 3) ^ (prow & 7);
                    sP[w * 2048 + prow * 64 + x * 8 + (col & 7)] = (bf16)pv[mi][nj][r];
                }
            }

        // O += P V
#pragma unroll
        for (int kq2 = 0; kq2 < 2; kq2++) {
            bf16x8 pf[2];
#pragma unroll
            for (int mi = 0; mi < 2; mi++) {
                int r = mi * 16 + l15;
                int x = (kq2 * 4 + quad) ^ (r & 7);
                pf[mi] = *(const bf16x8*)(sP + w * 2048 + r * 64 + x * 8);
            }
#pragma unroll
            for (int ni = 0; ni < 8; ni++) {
                int r = ni * 16 + l15;
                int x = (kq2 * 4 + quad) ^ (r & 7);
                bf16x8 vf = *(const bf16x8*)(sV + r * 64 + x * 8);
#pragma unroll
                for (int mi = 0; mi < 2; mi++)
                    oacc[mi][ni] = MFMA_BF16(pf[mi], vf, oacc[mi][ni]);
            }
        }
        __syncthreads();
    }

    // epilogue: O /= l, store [b, s, h*128+d]
#pragma unroll
    for (int mi = 0; mi < 2; mi++)
#pragma unroll
        for (int r = 0; r < 4; r++) {
            int s = rowbase + mi * 16 + quad * 4 + r;
            float inv = 1.0f / l_s[mi][r];
            size_t base = ((size_t)(b * 2048 + s)) * 2048 + h * 128;
#pragma unroll
            for (int ni = 0; ni < 8; ni++)
                O[base + ni * 16 + l15] = (bf16)(oacc[mi][ni][r] * inv);
        }
}

extern "C" void kernel_launch(void* const* d_in, const int* in_sizes, int n_in,
                              void* d_out, int out_size, void* d_ws, size_t ws_size,
                              hipStream_t stream) {
    const float* x     = (const float*)d_in[0];
    const int*   am    = (const int*)d_in[1];
    const float* qkvw  = (const float*)d_in[2];
    const float* qkvb  = (const float*)d_in[3];
    const float* outw  = (const float*)d_in[4];
    const float* outb  = (const float*)d_in[5];
    float* out = (float*)d_out;

    char* ws = (char*)d_ws;
    bf16*  xb    = (bf16*)(ws);                          // 16 MB  x bf16 [4096,2048]
    bf16*  wqkv  = (bf16*)(ws + (16ull << 20));          // 24 MB  qkv_w bf16 [6144,2048]
    bf16*  wout  = (bf16*)(ws + (40ull << 20));          //  8 MB  out_w bf16 [2048,2048]
    bf16*  qb    = (bf16*)(ws + (48ull << 20));          // 16 MB  q   [32, 2048, 128]
    bf16*  kb    = (bf16*)(ws + (64ull << 20));          // 16 MB  k   [32, 2048, 128]
    bf16*  vtb   = (bf16*)(ws + (80ull << 20));          // 16 MB  v^T [32, 128, 2048]
    bf16*  attn  = (bf16*)(ws + (96ull << 20));          // 16 MB  attn [4096, 2048]
    float* cosT  = (float*)(ws + (112ull << 20));        //  1 MB
    float* sinT  = (float*)(ws + (113ull << 20));        //  1 MB
    float* mbias = (float*)(ws + (114ull << 20));        // 16 KB

    cvt8<<<4096, 256, 0, stream>>>(x, xb, 4096 * 2048);
    cvt8<<<6144, 256, 0, stream>>>(qkvw, wqkv, 6144 * 2048);
    cvt8<<<2048, 256, 0, stream>>>(outw, wout, 2048 * 2048);
    tables_k<<<1024, 256, 0, stream>>>(am, cosT, sinT, mbias);

    gemm_bt<1><<<dim3(32, 48), 256, 0, stream>>>(
        xb, wqkv, qkvb, nullptr, qb, kb, vtb, cosT, sinT, 4096, 6144, 2048);

    fattn<<<dim3(16, 32), 256, 0, stream>>>(qb, kb, vtb, mbias, attn);

    gemm_bt<0><<<dim3(32, 16), 256, 0, stream>>>(
        attn, wout, outb, out, nullptr, nullptr, nullptr, nullptr, nullptr,
        4096, 2048, 2048);
}

// Round 2
// 451.077 us; speedup vs baseline: 1.0288x; 1.0288x over previous
//
#include <hip/hip_runtime.h>

typedef __bf16 bf16;
typedef __bf16 bf16x8 __attribute__((ext_vector_type(8)));
typedef float f32x4 __attribute__((ext_vector_type(4)));

#define MFMA_BF16(a, b, c) __builtin_amdgcn_mfma_f32_16x16x32_bf16(a, b, c, 0, 0, 0)

__device__ __forceinline__ void async16(const void* g, void* l) {
    __builtin_amdgcn_global_load_lds(
        (const __attribute__((address_space(1))) void*)g,
        (__attribute__((address_space(3))) void*)l,
        16, 0, 0);
}

// ---------------- fp32 -> bf16 convert, 8 elems/thread ----------------
__global__ void cvt8(const float* __restrict__ in, bf16* __restrict__ out, int n) {
    int i = (blockIdx.x * 256 + threadIdx.x) * 8;
    if (i >= n) return;
    float4 a = *(const float4*)(in + i);
    float4 b = *(const float4*)(in + i + 4);
    bf16x8 o;
    o[0] = (bf16)a.x; o[1] = (bf16)a.y; o[2] = (bf16)a.z; o[3] = (bf16)a.w;
    o[4] = (bf16)b.x; o[5] = (bf16)b.y; o[6] = (bf16)b.z; o[7] = (bf16)b.w;
    *(bf16x8*)(out + i) = o;
}

// ---------------- RoPE tables (S=2048, hd=128) + key-mask bias ----------------
__global__ void tables_k(const int* __restrict__ am, float* __restrict__ cosT,
                         float* __restrict__ sinT, float* __restrict__ mbias) {
    int i = blockIdx.x * 256 + threadIdx.x;   // 0 .. 2048*128-1
    int s = i >> 7, d = i & 127, fi = d & 63;
    // inv_freq = 10000^(-fi/64) = exp2(-fi * log2(10000)/64)
    float inv = exp2f(-(float)fi * (13.287712379549449f / 64.0f));
    float ang = (float)s * inv;
    cosT[i] = cosf(ang);
    sinT[i] = sinf(ang);
    if (i < 2 * 2048) mbias[i] = (am[i] == 0) ? -1e30f : 0.0f;
}

// ---------------- GEMM: C[M,N] = A[M,K] @ Bt[N,K]^T + bias ----------------
// 128x128 tile, BK=64, 4 waves (2x2), each wave 64x64 via 4x4 of 16x16x32 MFMA.
// LDS xor-swizzled on 16B chunks: chunk x holds global chunk g = x ^ (row&7).
// EPI=0: fp32 store to Cf.  EPI=1: fused RoPE + scatter to q[bh,s,d], k[bh,s,d], vt[bh,d,s].
template <int EPI>
__global__ void __launch_bounds__(256, 2)
gemm_bt(const bf16* __restrict__ A, const bf16* __restrict__ Bt,
        const float* __restrict__ bias, float* __restrict__ Cf,
        bf16* __restrict__ qb, bf16* __restrict__ kb, bf16* __restrict__ vtb,
        const float* __restrict__ cosT, const float* __restrict__ sinT,
        int M, int N, int K) {
    __shared__ __align__(16) bf16 sA[128 * 64];
    __shared__ __align__(16) bf16 sB[128 * 64];
    const int tid  = threadIdx.x;
    const int lane = tid & 63;
    const int quad = lane >> 4, l15 = lane & 15;
    const int wid = tid >> 6, wm = wid >> 1, wn = wid & 1;
    const int bm = blockIdx.x, bn = blockIdx.y;

    f32x4 acc[4][4];
#pragma unroll
    for (int i = 0; i < 4; i++)
#pragma unroll
        for (int j = 0; j < 4; j++)
#pragma unroll
            for (int c = 0; c < 4; c++) acc[i][j][c] = 0.0f;

    // staging: 1024 chunks (16B) per 128x64 tile -> 4 insts x 256 threads
    const int r0 = tid >> 3, x0 = tid & 7;
    const int g0 = x0 ^ (r0 & 7);            // (r0+32i)&7 == r0&7
    const bf16* pa = A  + (size_t)(bm * 128 + r0) * K + g0 * 8;
    const bf16* pb = Bt + (size_t)(bn * 128 + r0) * K + g0 * 8;
    bf16* la = sA + tid * 8;
    bf16* lb = sB + tid * 8;
    const size_t gstep = (size_t)32 * K;

    for (int k0 = 0; k0 < K; k0 += 64) {
#pragma unroll
        for (int i = 0; i < 4; i++) {
            async16(pa + i * gstep, la + i * 2048);
            async16(pb + i * gstep, lb + i * 2048);
        }
        pa += 64; pb += 64;
        __syncthreads();
#pragma unroll
        for (int ks = 0; ks < 2; ks++) {
            bf16x8 af[4], bfr[4];
#pragma unroll
            for (int i = 0; i < 4; i++) {
                int r = wm * 64 + i * 16 + l15;
                int x = (ks * 4 + quad) ^ (r & 7);
                af[i] = *(const bf16x8*)(sA + r * 64 + x * 8);
            }
#pragma unroll
            for (int i = 0; i < 4; i++) {
                int r = wn * 64 + i * 16 + l15;
                int x = (ks * 4 + quad) ^ (r & 7);
                bfr[i] = *(const bf16x8*)(sB + r * 64 + x * 8);
            }
#pragma unroll
            for (int mi = 0; mi < 4; mi++)
#pragma unroll
                for (int ni = 0; ni < 4; ni++)
                    acc[mi][ni] = MFMA_BF16(af[mi], bfr[ni], acc[mi][ni]);
        }
        __syncthreads();
    }

    if (EPI == 0) {
#pragma unroll
        for (int mi = 0; mi < 4; mi++)
#pragma unroll
            for (int ni = 0; ni < 4; ni++) {
                int row0 = bm * 128 + wm * 64 + mi * 16 + quad * 4;
                int col  = bn * 128 + wn * 64 + ni * 16 + l15;
                float bv = bias[col];
#pragma unroll
                for (int r = 0; r < 4; r++)
                    Cf[(size_t)(row0 + r) * N + col] = acc[mi][ni][r] + bv;
            }
    } else {
        // QKV epilogue: col -> (which, head, d); row -> (b, s). RoPE on q,k.
#pragma unroll
        for (int mi = 0; mi < 4; mi++)
#pragma unroll
            for (int ni = 0; ni < 4; ni++) {
                int col   = bn * 128 + wn * 64 + ni * 16 + l15;
                int which = col >> 11;
                int hcol  = col & 2047;
                int h = hcol >> 7, d = hcol & 127;
                float bv = bias[col];
#pragma unroll
                for (int r = 0; r < 4; r++) {
                    int row = bm * 128 + wm * 64 + mi * 16 + quad * 4 + r;
                    int b = row >> 11, s = row & 2047;
                    float v  = acc[mi][ni][r] + bv;
                    float vp = __shfl_xor(v, 1, 64);   // partner column d^1
                    float ov = v;
                    if (which < 2) {
                        float c  = cosT[(s << 7) + d];
                        float sn = sinT[(s << 7) + d];
                        // out[2i] = v*cos - v[2i+1]*sin ; out[2i+1] = v*cos + v[2i]*sin
                        ov = v * c + ((d & 1) ? vp : -vp) * sn;
                    }
                    size_t bh = (size_t)(b * 16 + h);
                    if (which == 0)      qb[(bh * 2048 + s) * 128 + d] = (bf16)ov;
                    else if (which == 1) kb[(bh * 2048 + s) * 128 + d] = (bf16)ov;
                    else                 vtb[(bh * 128 + d) * 2048 + s] = (bf16)ov;
                }
            }
    }
}

// ---------------- Flash attention (causal), S=2048, hd=128, BM=64, BN=64 ----------------
// One block = 4 waves, each wave owns 16 q-rows x full hd=128.
// q [bh, s, d], k [bh, s, d], vt [bh, d, s]; out attn [b, s, h*128+d] bf16.
// LDS: sK 16K + sV 16K + sP 8K = 40KB -> 4 blocks/CU. Grid 32x32 = 1024 blocks.
__global__ void __launch_bounds__(256, 4)
fattn(const bf16* __restrict__ Q, const bf16* __restrict__ Kg,
      const bf16* __restrict__ Vt, const float* __restrict__ mbias,
      bf16* __restrict__ O) {
    __shared__ __align__(16) bf16 sK[64 * 128];
    __shared__ __align__(16) bf16 sV[128 * 64];
    __shared__ __align__(16) bf16 sP[4 * 16 * 64];
    const int tid = threadIdx.x, lane = tid & 63, w = tid >> 6;
    const int quad = lane >> 4, l15 = lane & 15;
    const int qt = 31 - (int)blockIdx.x;      // heavy (late-diagonal) blocks first
    const int bh = blockIdx.y;
    const int b = bh >> 4, h = bh & 15;
    const int rowbase = qt * 64 + w * 16;     // this wave's 16 q-rows

    const bf16* Qb  = Q  + (size_t)bh * 2048 * 128;
    const bf16* Kbh = Kg + (size_t)bh * 2048 * 128;
    const bf16* Vbh = Vt + (size_t)bh * 128 * 2048;
    const float* mbb = mbias + b * 2048;

    // resident Q fragments: 1 row-tile x 4 k-steps
    bf16x8 qf[4];
#pragma unroll
    for (int kq = 0; kq < 4; kq++)
        qf[kq] = *(const bf16x8*)(Qb + (size_t)(rowbase + l15) * 128 + kq * 32 + quad * 8);

    f32x4 oacc[8];
#pragma unroll
    for (int ni = 0; ni < 8; ni++)
#pragma unroll
        for (int c = 0; c < 4; c++) oacc[ni][c] = 0.0f;
    float m_s[4], l_s[4];
#pragma unroll
    for (int r = 0; r < 4; r++) { m_s[r] = -3e38f; l_s[r] = 0.0f; }

    const int rk = tid >> 4, xk = tid & 15, gk = xk ^ (rk & 15);  // K tile: 16 chunks/row
    const int rv = tid >> 3, xv = tid & 7,  gv = xv ^ (rv & 7);   // V tile: 8 chunks/row
    const int nkt = qt + 1;

    for (int kt = 0; kt < nkt; kt++) {
        const int kb0 = kt * 64;
#pragma unroll
        for (int i = 0; i < 4; i++) {
            async16(Kbh + (size_t)(kb0 + rk + i * 16) * 128 + gk * 8, sK + (i * 256 + tid) * 8);
            async16(Vbh + (size_t)(rv + i * 32) * 2048 + kb0 + gv * 8, sV + (i * 256 + tid) * 8);
        }
        __syncthreads();

        // S = Q K^T  (16 rows x 64 keys per wave)
        f32x4 sacc[4];
#pragma unroll
        for (int nj = 0; nj < 4; nj++)
#pragma unroll
            for (int c = 0; c < 4; c++) sacc[nj][c] = 0.0f;
#pragma unroll
        for (int kq = 0; kq < 4; kq++) {
            bf16x8 kf[4];
#pragma unroll
            for (int nj = 0; nj < 4; nj++) {
                int r = nj * 16 + l15;
                int x = (kq * 4 + quad) ^ (r & 15);
                kf[nj] = *(const bf16x8*)(sK + r * 128 + x * 8);
            }
#pragma unroll
            for (int nj = 0; nj < 4; nj++)
                sacc[nj] = MFMA_BF16(qf[kq], kf[nj], sacc[nj]);
        }

        // scale + causal/key mask
        float pv[4][4];
#pragma unroll
        for (int nj = 0; nj < 4; nj++) {
            int sk = kb0 + nj * 16 + l15;
            float mbv = mbb[sk];
#pragma unroll
            for (int r = 0; r < 4; r++) {
                int sq = rowbase + quad * 4 + r;
                float val = sacc[nj][r] * 0.08838834764831845f + mbv;
                pv[nj][r] = (sk > sq) ? -1e30f : val;
            }
        }

        // online softmax per row (row shared by the 16 lanes of a quad)
#pragma unroll
        for (int r = 0; r < 4; r++) {
            float mx = fmaxf(fmaxf(pv[0][r], pv[1][r]), fmaxf(pv[2][r], pv[3][r]));
#pragma unroll
            for (int off = 1; off <= 8; off <<= 1)
                mx = fmaxf(mx, __shfl_xor(mx, off, 64));
            float mnew  = fmaxf(m_s[r], mx);
            float alpha = __expf(m_s[r] - mnew);
            float rs = 0.0f;
#pragma unroll
            for (int nj = 0; nj < 4; nj++) {
                float p = __expf(pv[nj][r] - mnew);
                pv[nj][r] = p;
                rs += p;
            }
#pragma unroll
            for (int off = 1; off <= 8; off <<= 1)
                rs += __shfl_xor(rs, off, 64);
            l_s[r] = l_s[r] * alpha + rs;
            m_s[r] = mnew;
#pragma unroll
            for (int ni = 0; ni < 8; ni++) oacc[ni][r] *= alpha;
            // write P (bf16) to per-wave LDS, swizzled rows of 8 chunks
            int prow = quad * 4 + r;
#pragma unroll
            for (int nj = 0; nj < 4; nj++) {
                int col = nj * 16 + l15;
                int x = (col >> 3) ^ (prow & 7);
                sP[w * 1024 + prow * 64 + x * 8 + (col & 7)] = (bf16)pv[nj][r];
            }
        }

        // O += P V
#pragma unroll
        for (int kq2 = 0; kq2 < 2; kq2++) {
            int rp = l15;
            int xp = (kq2 * 4 + quad) ^ (rp & 7);
            bf16x8 pf = *(const bf16x8*)(sP + w * 1024 + rp * 64 + xp * 8);
#pragma unroll
            for (int ni = 0; ni < 8; ni++) {
                int r = ni * 16 + l15;
                int x = (kq2 * 4 + quad) ^ (r & 7);
                bf16x8 vf = *(const bf16x8*)(sV + r * 64 + x * 8);
                oacc[ni] = MFMA_BF16(pf, vf, oacc[ni]);
            }
        }
        __syncthreads();
    }

    // epilogue: O /= l, store [b, s, h*128+d]
#pragma unroll
    for (int r = 0; r < 4; r++) {
        int s = rowbase + quad * 4 + r;
        float inv = 1.0f / l_s[r];
        size_t base = ((size_t)(b * 2048 + s)) * 2048 + h * 128;
#pragma unroll
        for (int ni = 0; ni < 8; ni++)
            O[base + ni * 16 + l15] = (bf16)(oacc[ni][r] * inv);
    }
}

extern "C" void kernel_launch(void* const* d_in, const int* in_sizes, int n_in,
                              void* d_out, int out_size, void* d_ws, size_t ws_size,
                              hipStream_t stream) {
    const float* x     = (const float*)d_in[0];
    const int*   am    = (const int*)d_in[1];
    const float* qkvw  = (const float*)d_in[2];
    const float* qkvb  = (const float*)d_in[3];
    const float* outw  = (const float*)d_in[4];
    const float* outb  = (const float*)d_in[5];
    float* out = (float*)d_out;

    char* ws = (char*)d_ws;
    bf16*  xb    = (bf16*)(ws);                          // 16 MB  x bf16 [4096,2048]
    bf16*  wqkv  = (bf16*)(ws + (16ull << 20));          // 24 MB  qkv_w bf16 [6144,2048]
    bf16*  wout  = (bf16*)(ws + (40ull << 20));          //  8 MB  out_w bf16 [2048,2048]
    bf16*  qb    = (bf16*)(ws + (48ull << 20));          // 16 MB  q   [32, 2048, 128]
    bf16*  kb    = (bf16*)(ws + (64ull << 20));          // 16 MB  k   [32, 2048, 128]
    bf16*  vtb   = (bf16*)(ws + (80ull << 20));          // 16 MB  v^T [32, 128, 2048]
    bf16*  attn  = (bf16*)(ws + (96ull << 20));          // 16 MB  attn [4096, 2048]
    float* cosT  = (float*)(ws + (112ull << 20));        //  1 MB
    float* sinT  = (float*)(ws + (113ull << 20));        //  1 MB
    float* mbias = (float*)(ws + (114ull << 20));        // 16 KB

    cvt8<<<4096, 256, 0, stream>>>(x, xb, 4096 * 2048);
    cvt8<<<6144, 256, 0, stream>>>(qkvw, wqkv, 6144 * 2048);
    cvt8<<<2048, 256, 0, stream>>>(outw, wout, 2048 * 2048);
    tables_k<<<1024, 256, 0, stream>>>(am, cosT, sinT, mbias);

    gemm_bt<1><<<dim3(32, 48), 256, 0, stream>>>(
        xb, wqkv, qkvb, nullptr, qb, kb, vtb, cosT, sinT, 4096, 6144, 2048);

    fattn<<<dim3(32, 32), 256, 0, stream>>>(qb, kb, vtb, mbias, attn);

    gemm_bt<0><<<dim3(32, 16), 256, 0, stream>>>(
        attn, wout, outb, out, nullptr, nullptr, nullptr, nullptr, nullptr,
        4096, 2048, 2048);
}

// Round 3
// 429.451 us; speedup vs baseline: 1.0806x; 1.0504x over previous
//
#include <hip/hip_runtime.h>

typedef __bf16 bf16;
typedef __bf16 bf16x4 __attribute__((ext_vector_type(4)));
typedef __bf16 bf16x8 __attribute__((ext_vector_type(8)));
typedef float f32x4 __attribute__((ext_vector_type(4)));

#define MFMA_BF16(a, b, c) __builtin_amdgcn_mfma_f32_16x16x32_bf16(a, b, c, 0, 0, 0)

__device__ __forceinline__ void async16(const void* g, void* l) {
    __builtin_amdgcn_global_load_lds(
        (const __attribute__((address_space(1))) void*)g,
        (__attribute__((address_space(3))) void*)l,
        16, 0, 0);
}

// ---------------- fp32 -> bf16 convert, 8 elems/thread ----------------
__global__ void cvt8(const float* __restrict__ in, bf16* __restrict__ out, int n) {
    int i = (blockIdx.x * 256 + threadIdx.x) * 8;
    if (i >= n) return;
    float4 a = *(const float4*)(in + i);
    float4 b = *(const float4*)(in + i + 4);
    bf16x8 o;
    o[0] = (bf16)a.x; o[1] = (bf16)a.y; o[2] = (bf16)a.z; o[3] = (bf16)a.w;
    o[4] = (bf16)b.x; o[5] = (bf16)b.y; o[6] = (bf16)b.z; o[7] = (bf16)b.w;
    *(bf16x8*)(out + i) = o;
}

// ---------------- RoPE tables (S=2048, hd=128) + key-mask bias ----------------
__global__ void tables_k(const int* __restrict__ am, float* __restrict__ cosT,
                         float* __restrict__ sinT, float* __restrict__ mbias) {
    int i = blockIdx.x * 256 + threadIdx.x;   // 0 .. 2048*128-1
    int s = i >> 7, d = i & 127, fi = d & 63;
    float inv = exp2f(-(float)fi * (13.287712379549449f / 64.0f));
    float ang = (float)s * inv;
    cosT[i] = cosf(ang);
    sinT[i] = sinf(ang);
    if (i < 2 * 2048) mbias[i] = (am[i] == 0) ? -1e30f : 0.0f;
}

// ---------------- GEMM: C[M,N] = A[M,K] @ Bt[N,K]^T + bias ----------------
// 128x128 tile, BK=64, 4 waves (2x2), each wave 64x64 via 4x4 of 16x16x32 MFMA.
// LDS xor-swizzled on 16B chunks: chunk x holds global chunk g = x ^ (row&7).
// EPI=0: fp32 store.  EPI=1: fused RoPE (+1/sqrt(d) scale on q) + scatter.
template <int EPI>
__global__ void __launch_bounds__(256, 2)
gemm_bt(const bf16* __restrict__ A, const bf16* __restrict__ Bt,
        const float* __restrict__ bias, float* __restrict__ Cf,
        bf16* __restrict__ qb, bf16* __restrict__ kb, bf16* __restrict__ vtb,
        const float* __restrict__ cosT, const float* __restrict__ sinT,
        int M, int N, int K) {
    __shared__ __align__(16) bf16 sA[128 * 64];
    __shared__ __align__(16) bf16 sB[128 * 64];
    const int tid  = threadIdx.x;
    const int lane = tid & 63;
    const int quad = lane >> 4, l15 = lane & 15;
    const int wid = tid >> 6, wm = wid >> 1, wn = wid & 1;
    const int bm = blockIdx.x, bn = blockIdx.y;

    f32x4 acc[4][4];
#pragma unroll
    for (int i = 0; i < 4; i++)
#pragma unroll
        for (int j = 0; j < 4; j++)
#pragma unroll
            for (int c = 0; c < 4; c++) acc[i][j][c] = 0.0f;

    const int r0 = tid >> 3, x0 = tid & 7;
    const int g0 = x0 ^ (r0 & 7);
    const bf16* pa = A  + (size_t)(bm * 128 + r0) * K + g0 * 8;
    const bf16* pb = Bt + (size_t)(bn * 128 + r0) * K + g0 * 8;
    bf16* la = sA + tid * 8;
    bf16* lb = sB + tid * 8;
    const size_t gstep = (size_t)32 * K;

    for (int k0 = 0; k0 < K; k0 += 64) {
#pragma unroll
        for (int i = 0; i < 4; i++) {
            async16(pa + i * gstep, la + i * 2048);
            async16(pb + i * gstep, lb + i * 2048);
        }
        pa += 64; pb += 64;
        __syncthreads();
#pragma unroll
        for (int ks = 0; ks < 2; ks++) {
            bf16x8 af[4], bfr[4];
#pragma unroll
            for (int i = 0; i < 4; i++) {
                int r = wm * 64 + i * 16 + l15;
                int x = (ks * 4 + quad) ^ (r & 7);
                af[i] = *(const bf16x8*)(sA + r * 64 + x * 8);
            }
#pragma unroll
            for (int i = 0; i < 4; i++) {
                int r = wn * 64 + i * 16 + l15;
                int x = (ks * 4 + quad) ^ (r & 7);
                bfr[i] = *(const bf16x8*)(sB + r * 64 + x * 8);
            }
#pragma unroll
            for (int mi = 0; mi < 4; mi++)
#pragma unroll
                for (int ni = 0; ni < 4; ni++)
                    acc[mi][ni] = MFMA_BF16(af[mi], bfr[ni], acc[mi][ni]);
        }
        __syncthreads();
    }

    if (EPI == 0) {
#pragma unroll
        for (int mi = 0; mi < 4; mi++)
#pragma unroll
            for (int ni = 0; ni < 4; ni++) {
                int row0 = bm * 128 + wm * 64 + mi * 16 + quad * 4;
                int col  = bn * 128 + wn * 64 + ni * 16 + l15;
                float bv = bias[col];
#pragma unroll
                for (int r = 0; r < 4; r++)
                    Cf[(size_t)(row0 + r) * N + col] = acc[mi][ni][r] + bv;
            }
    } else {
#pragma unroll
        for (int mi = 0; mi < 4; mi++)
#pragma unroll
            for (int ni = 0; ni < 4; ni++) {
                int col   = bn * 128 + wn * 64 + ni * 16 + l15;
                int which = col >> 11;
                int hcol  = col & 2047;
                int h = hcol >> 7, d = hcol & 127;
                float bv = bias[col];
#pragma unroll
                for (int r = 0; r < 4; r++) {
                    int row = bm * 128 + wm * 64 + mi * 16 + quad * 4 + r;
                    int b = row >> 11, s = row & 2047;
                    float v  = acc[mi][ni][r] + bv;
                    float vp = __shfl_xor(v, 1, 64);   // partner column d^1
                    float ov = v;
                    if (which < 2) {
                        float c  = cosT[(s << 7) + d];
                        float sn = sinT[(s << 7) + d];
                        ov = v * c + ((d & 1) ? vp : -vp) * sn;
                    }
                    if (which == 0) ov *= 0.08838834764831845f;  // fold 1/sqrt(hd)
                    size_t bh = (size_t)(b * 16 + h);
                    if (which == 0)      qb[(bh * 2048 + s) * 128 + d] = (bf16)ov;
                    else if (which == 1) kb[(bh * 2048 + s) * 128 + d] = (bf16)ov;
                    else                 vtb[(bh * 128 + d) * 2048 + s] = (bf16)ov;
                }
            }
    }
}

// ---------------- Flash attention (causal), S^T/O^T form ----------------
// S=2048, hd=128, BM=64 (16 q-rows/wave), BN=64. Grid 32x32, 4 blocks/CU.
// S^T = MFMA(K-frag, Q-frag): C col(l15)=query, rows(quad,reg)=keys -> softmax
// reduction is 15 in-lane ops + 2 shuffles (vs 32 shuffles in S-form).
// O^T = MFMA(Vt-frag, P-frag): col=query, rows=d.
__global__ void __launch_bounds__(256, 4)
fattn(const bf16* __restrict__ Q, const bf16* __restrict__ Kg,
      const bf16* __restrict__ Vt, const float* __restrict__ mbias,
      bf16* __restrict__ O) {
    __shared__ __align__(16) bf16 sK[64 * 128];
    __shared__ __align__(16) bf16 sV[128 * 64];
    __shared__ __align__(16) bf16 sP[4 * 16 * 64];   // per-wave [q=16][key=64]
    const int tid = threadIdx.x, lane = tid & 63, w = tid >> 6;
    const int quad = lane >> 4, l15 = lane & 15;
    const int qt = 31 - (int)blockIdx.x;      // heavy (late-diagonal) blocks first
    const int bh = blockIdx.y;
    const int b = bh >> 4, h = bh & 15;
    const int rowbase = qt * 64 + w * 16;     // this wave's 16 q-rows
    const int myq = rowbase + l15;            // this lane's query row

    const bf16* Qb  = Q  + (size_t)bh * 2048 * 128;
    const bf16* Kbh = Kg + (size_t)bh * 2048 * 128;
    const bf16* Vbh = Vt + (size_t)bh * 128 * 2048;
    const float* mbb = mbias + b * 2048;

    // resident Q fragments (B-operand: lane l15 = query, quad = k-chunk)
    bf16x8 qf[4];
#pragma unroll
    for (int kq = 0; kq < 4; kq++)
        qf[kq] = *(const bf16x8*)(Qb + (size_t)myq * 128 + kq * 32 + quad * 8);

    f32x4 oacc[8];   // O^T: tile ni -> d = ni*16 + quad*4 + reg, col = query l15
#pragma unroll
    for (int ni = 0; ni < 8; ni++)
#pragma unroll
        for (int c = 0; c < 4; c++) oacc[ni][c] = 0.0f;
    float m_s = -3e38f, l_s = 0.0f;          // per-lane (lane = one query)

    const int rk = tid >> 4, xk = tid & 15, gk = xk ^ (rk & 15);
    const int rv = tid >> 3, xv = tid & 7,  gv = xv ^ (rv & 7);
    const int nkt = qt + 1;

    for (int kt = 0; kt < nkt; kt++) {
        const int kb0 = kt * 64;
#pragma unroll
        for (int i = 0; i < 4; i++) {
            async16(Kbh + (size_t)(kb0 + rk + i * 16) * 128 + gk * 8, sK + (i * 256 + tid) * 8);
            async16(Vbh + (size_t)(rv + i * 32) * 2048 + kb0 + gv * 8, sV + (i * 256 + tid) * 8);
        }
        __syncthreads();

        // S^T: rows = keys (in-register), col = query (l15)
        f32x4 sacc[4];
#pragma unroll
        for (int nj = 0; nj < 4; nj++)
#pragma unroll
            for (int c = 0; c < 4; c++) sacc[nj][c] = 0.0f;
#pragma unroll
        for (int kq = 0; kq < 4; kq++) {
            bf16x8 kf[4];
#pragma unroll
            for (int nj = 0; nj < 4; nj++) {
                int r = nj * 16 + l15;
                int x = (kq * 4 + quad) ^ (r & 15);
                kf[nj] = *(const bf16x8*)(sK + r * 128 + x * 8);
            }
#pragma unroll
            for (int nj = 0; nj < 4; nj++)
                sacc[nj] = MFMA_BF16(kf[nj], qf[kq], sacc[nj]);
        }

        // mask (key-mask bias + causal); scale already folded into q
        float pv[4][4];
#pragma unroll
        for (int nj = 0; nj < 4; nj++) {
            float4 mb4 = *(const float4*)(mbb + kb0 + nj * 16 + quad * 4);
#pragma unroll
            for (int r = 0; r < 4; r++) {
                int sk = kb0 + nj * 16 + quad * 4 + r;
                float val = sacc[nj][r] + ((const float*)&mb4)[r];
                pv[nj][r] = (sk > myq) ? -1e30f : val;
            }
        }

        // online softmax: 16 in-lane values, then 2 cross-quad shuffles
        float mx = -3e38f;
#pragma unroll
        for (int nj = 0; nj < 4; nj++)
#pragma unroll
            for (int r = 0; r < 4; r++) mx = fmaxf(mx, pv[nj][r]);
        mx = fmaxf(mx, __shfl_xor(mx, 16, 64));
        mx = fmaxf(mx, __shfl_xor(mx, 32, 64));
        float mnew  = fmaxf(m_s, mx);
        float alpha = __expf(m_s - mnew);
        float rs = 0.0f;
#pragma unroll
        for (int nj = 0; nj < 4; nj++)
#pragma unroll
            for (int r = 0; r < 4; r++) {
                float p = __expf(pv[nj][r] - mnew);
                pv[nj][r] = p;
                rs += p;
            }
        rs += __shfl_xor(rs, 16, 64);
        rs += __shfl_xor(rs, 32, 64);
        l_s = l_s * alpha + rs;
        m_s = mnew;
#pragma unroll
        for (int ni = 0; ni < 8; ni++) oacc[ni] *= alpha;

        // write P to per-wave LDS [q=l15][key], xor-swizzled 8-elem chunks
#pragma unroll
        for (int nj = 0; nj < 4; nj++) {
            int chunk = nj * 2 + (quad >> 1);          // key>>3
            int x = chunk ^ (l15 & 7);
            bf16* dst = sP + w * 1024 + l15 * 64 + x * 8 + (quad & 1) * 4;
#pragma unroll
            for (int r = 0; r < 4; r++) dst[r] = (bf16)pv[nj][r];
        }

        // O^T += V^T P : A = vf (m=d), B = pf (n=q)
#pragma unroll
        for (int kq2 = 0; kq2 < 2; kq2++) {
            int xp = (kq2 * 4 + quad) ^ (l15 & 7);
            bf16x8 pf = *(const bf16x8*)(sP + w * 1024 + l15 * 64 + xp * 8);
#pragma unroll
            for (int ni = 0; ni < 8; ni++) {
                int r = ni * 16 + l15;
                int x = (kq2 * 4 + quad) ^ (r & 7);
                bf16x8 vf = *(const bf16x8*)(sV + r * 64 + x * 8);
                oacc[ni] = MFMA_BF16(vf, pf, oacc[ni]);
            }
        }
        __syncthreads();
    }

    // epilogue: lane = query myq; d = ni*16 + quad*4 + reg. 8B packed stores.
    float inv = 1.0f / l_s;
    size_t base = ((size_t)(b * 2048 + myq)) * 2048 + h * 128;
#pragma unroll
    for (int ni = 0; ni < 8; ni++) {
        bf16x4 o4;
#pragma unroll
        for (int r = 0; r < 4; r++) o4[r] = (bf16)(oacc[ni][r] * inv);
        *(bf16x4*)(O + base + ni * 16 + quad * 4) = o4;
    }
}

extern "C" void kernel_launch(void* const* d_in, const int* in_sizes, int n_in,
                              void* d_out, int out_size, void* d_ws, size_t ws_size,
                              hipStream_t stream) {
    const float* x     = (const float*)d_in[0];
    const int*   am    = (const int*)d_in[1];
    const float* qkvw  = (const float*)d_in[2];
    const float* qkvb  = (const float*)d_in[3];
    const float* outw  = (const float*)d_in[4];
    const float* outb  = (const float*)d_in[5];
    float* out = (float*)d_out;

    char* ws = (char*)d_ws;
    bf16*  xb    = (bf16*)(ws);                          // 16 MB  x bf16 [4096,2048]
    bf16*  wqkv  = (bf16*)(ws + (16ull << 20));          // 24 MB  qkv_w bf16 [6144,2048]
    bf16*  wout  = (bf16*)(ws + (40ull << 20));          //  8 MB  out_w bf16 [2048,2048]
    bf16*  qb    = (bf16*)(ws + (48ull << 20));          // 16 MB  q   [32, 2048, 128] (pre-scaled)
    bf16*  kb    = (bf16*)(ws + (64ull << 20));          // 16 MB  k   [32, 2048, 128]
    bf16*  vtb   = (bf16*)(ws + (80ull << 20));          // 16 MB  v^T [32, 128, 2048]
    bf16*  attn  = (bf16*)(ws + (96ull << 20));          // 16 MB  attn [4096, 2048]
    float* cosT  = (float*)(ws + (112ull << 20));        //  1 MB
    float* sinT  = (float*)(ws + (113ull << 20));        //  1 MB
    float* mbias = (float*)(ws + (114ull << 20));        // 16 KB

    cvt8<<<4096, 256, 0, stream>>>(x, xb, 4096 * 2048);
    cvt8<<<6144, 256, 0, stream>>>(qkvw, wqkv, 6144 * 2048);
    cvt8<<<2048, 256, 0, stream>>>(outw, wout, 2048 * 2048);
    tables_k<<<1024, 256, 0, stream>>>(am, cosT, sinT, mbias);

    gemm_bt<1><<<dim3(32, 48), 256, 0, stream>>>(
        xb, wqkv, qkvb, nullptr, qb, kb, vtb, cosT, sinT, 4096, 6144, 2048);

    fattn<<<dim3(32, 32), 256, 0, stream>>>(qb, kb, vtb, mbias, attn);

    gemm_bt<0><<<dim3(32, 16), 256, 0, stream>>>(
        attn, wout, outb, out, nullptr, nullptr, nullptr, nullptr, nullptr,
        4096, 2048, 2048);
}

// Round 4
// 413.409 us; speedup vs baseline: 1.1225x; 1.0388x over previous
//
#include <hip/hip_runtime.h>

typedef __bf16 bf16;
typedef __bf16 bf16x4 __attribute__((ext_vector_type(4)));
typedef __bf16 bf16x8 __attribute__((ext_vector_type(8)));
typedef float f32x4 __attribute__((ext_vector_type(4)));
typedef float f32x16 __attribute__((ext_vector_type(16)));

#define MFMA_BF16(a, b, c) __builtin_amdgcn_mfma_f32_16x16x32_bf16(a, b, c, 0, 0, 0)
#define MFMA32(a, b, c)    __builtin_amdgcn_mfma_f32_32x32x16_bf16(a, b, c, 0, 0, 0)

__device__ __forceinline__ void async16(const void* g, void* l) {
    __builtin_amdgcn_global_load_lds(
        (const __attribute__((address_space(1))) void*)g,
        (__attribute__((address_space(3))) void*)l,
        16, 0, 0);
}

// ---------------- fp32 -> bf16 convert, 8 elems/thread ----------------
__global__ void cvt8(const float* __restrict__ in, bf16* __restrict__ out, int n) {
    int i = (blockIdx.x * 256 + threadIdx.x) * 8;
    if (i >= n) return;
    float4 a = *(const float4*)(in + i);
    float4 b = *(const float4*)(in + i + 4);
    bf16x8 o;
    o[0] = (bf16)a.x; o[1] = (bf16)a.y; o[2] = (bf16)a.z; o[3] = (bf16)a.w;
    o[4] = (bf16)b.x; o[5] = (bf16)b.y; o[6] = (bf16)b.z; o[7] = (bf16)b.w;
    *(bf16x8*)(out + i) = o;
}

// ---------------- RoPE tables (S=2048, hd=128) + key-mask bias ----------------
__global__ void tables_k(const int* __restrict__ am, float* __restrict__ cosT,
                         float* __restrict__ sinT, float* __restrict__ mbias) {
    int i = blockIdx.x * 256 + threadIdx.x;   // 0 .. 2048*128-1
    int s = i >> 7, d = i & 127, fi = d & 63;
    float inv = exp2f(-(float)fi * (13.287712379549449f / 64.0f));
    float ang = (float)s * inv;
    cosT[i] = cosf(ang);
    sinT[i] = sinf(ang);
    if (i < 2 * 2048) mbias[i] = (am[i] == 0) ? -1e30f : 0.0f;
}

// ---------------- GEMM: C[M,N] = A[M,K] @ Bt[N,K]^T + bias ----------------
// (unchanged from R3 — at the m97-structure plateau, ~805 TF)
template <int EPI>
__global__ void __launch_bounds__(256, 2)
gemm_bt(const bf16* __restrict__ A, const bf16* __restrict__ Bt,
        const float* __restrict__ bias, float* __restrict__ Cf,
        bf16* __restrict__ qb, bf16* __restrict__ kb, bf16* __restrict__ vtb,
        const float* __restrict__ cosT, const float* __restrict__ sinT,
        int M, int N, int K) {
    __shared__ __align__(16) bf16 sA[128 * 64];
    __shared__ __align__(16) bf16 sB[128 * 64];
    const int tid  = threadIdx.x;
    const int lane = tid & 63;
    const int quad = lane >> 4, l15 = lane & 15;
    const int wid = tid >> 6, wm = wid >> 1, wn = wid & 1;
    const int bm = blockIdx.x, bn = blockIdx.y;

    f32x4 acc[4][4];
#pragma unroll
    for (int i = 0; i < 4; i++)
#pragma unroll
        for (int j = 0; j < 4; j++)
#pragma unroll
            for (int c = 0; c < 4; c++) acc[i][j][c] = 0.0f;

    const int r0 = tid >> 3, x0 = tid & 7;
    const int g0 = x0 ^ (r0 & 7);
    const bf16* pa = A  + (size_t)(bm * 128 + r0) * K + g0 * 8;
    const bf16* pb = Bt + (size_t)(bn * 128 + r0) * K + g0 * 8;
    bf16* la = sA + tid * 8;
    bf16* lb = sB + tid * 8;
    const size_t gstep = (size_t)32 * K;

    for (int k0 = 0; k0 < K; k0 += 64) {
#pragma unroll
        for (int i = 0; i < 4; i++) {
            async16(pa + i * gstep, la + i * 2048);
            async16(pb + i * gstep, lb + i * 2048);
        }
        pa += 64; pb += 64;
        __syncthreads();
#pragma unroll
        for (int ks = 0; ks < 2; ks++) {
            bf16x8 af[4], bfr[4];
#pragma unroll
            for (int i = 0; i < 4; i++) {
                int r = wm * 64 + i * 16 + l15;
                int x = (ks * 4 + quad) ^ (r & 7);
                af[i] = *(const bf16x8*)(sA + r * 64 + x * 8);
            }
#pragma unroll
            for (int i = 0; i < 4; i++) {
                int r = wn * 64 + i * 16 + l15;
                int x = (ks * 4 + quad) ^ (r & 7);
                bfr[i] = *(const bf16x8*)(sB + r * 64 + x * 8);
            }
#pragma unroll
            for (int mi = 0; mi < 4; mi++)
#pragma unroll
                for (int ni = 0; ni < 4; ni++)
                    acc[mi][ni] = MFMA_BF16(af[mi], bfr[ni], acc[mi][ni]);
        }
        __syncthreads();
    }

    if (EPI == 0) {
#pragma unroll
        for (int mi = 0; mi < 4; mi++)
#pragma unroll
            for (int ni = 0; ni < 4; ni++) {
                int row0 = bm * 128 + wm * 64 + mi * 16 + quad * 4;
                int col  = bn * 128 + wn * 64 + ni * 16 + l15;
                float bv = bias[col];
#pragma unroll
                for (int r = 0; r < 4; r++)
                    Cf[(size_t)(row0 + r) * N + col] = acc[mi][ni][r] + bv;
            }
    } else {
#pragma unroll
        for (int mi = 0; mi < 4; mi++)
#pragma unroll
            for (int ni = 0; ni < 4; ni++) {
                int col   = bn * 128 + wn * 64 + ni * 16 + l15;
                int which = col >> 11;
                int hcol  = col & 2047;
                int h = hcol >> 7, d = hcol & 127;
                float bv = bias[col];
#pragma unroll
                for (int r = 0; r < 4; r++) {
                    int row = bm * 128 + wm * 64 + mi * 16 + quad * 4 + r;
                    int b = row >> 11, s = row & 2047;
                    float v  = acc[mi][ni][r] + bv;
                    float vp = __shfl_xor(v, 1, 64);   // partner column d^1
                    float ov = v;
                    if (which < 2) {
                        float c  = cosT[(s << 7) + d];
                        float sn = sinT[(s << 7) + d];
                        ov = v * c + ((d & 1) ? vp : -vp) * sn;
                    }
                    if (which == 0) ov *= 0.08838834764831845f;  // fold 1/sqrt(hd)
                    size_t bh = (size_t)(b * 16 + h);
                    if (which == 0)      qb[(bh * 2048 + s) * 128 + d] = (bf16)ov;
                    else if (which == 1) kb[(bh * 2048 + s) * 128 + d] = (bf16)ov;
                    else                 vtb[(bh * 128 + d) * 2048 + s] = (bf16)ov;
                }
            }
    }
}

// ---------------- Flash attention v3: 32x32x16 MFMA, S^T/O^T form ----------------
// BM=128 (4 waves x 32 queries), BN=64 keys. Grid 16x32 = 512 blocks, 2/CU.
// qt pairing: adjacent block pairs sum to constant work (34 k-tiles).
// Layouts (m74/m101): C/D col=lane&31, row=(reg&3)+8*(reg>>2)+4*(lane>>5);
// A/B frag: m|n = lane&31, k = (lane>>5)*8 + j.
__global__ void __launch_bounds__(256, 2)
fattn(const bf16* __restrict__ Q, const bf16* __restrict__ Kg,
      const bf16* __restrict__ Vt, const float* __restrict__ mbias,
      bf16* __restrict__ O) {
    __shared__ __align__(16) bf16 sK[64 * 128];      // [key][d]
    __shared__ __align__(16) bf16 sV[128 * 64];      // [d][key]
    __shared__ __align__(16) bf16 sP[4 * 32 * 64];   // per-wave [q][key]
    const int tid = threadIdx.x, lane = tid & 63, w = tid >> 6;
    const int l31 = lane & 31, half = lane >> 5;
    const int bx = (int)blockIdx.x;
    const int qt = (bx & 1) ? 15 - (bx >> 1) : (bx >> 1);  // work pairing
    const int bh = blockIdx.y, b = bh >> 4, hh = bh & 15;
    const int myq = qt * 128 + w * 32 + l31;         // this lane's query row

    const bf16* Qb  = Q  + (size_t)bh * 2048 * 128;
    const bf16* Kbh = Kg + (size_t)bh * 2048 * 128;
    const bf16* Vbh = Vt + (size_t)bh * 128 * 2048;
    const float* mbb = mbias + b * 2048;
    bf16* sPw = sP + w * 2048;

    // resident Q fragments: B-operand, n=query(l31), k = kq*16 + half*8 + j
    bf16x8 qf[8];
#pragma unroll
    for (int kq = 0; kq < 8; kq++)
        qf[kq] = *(const bf16x8*)(Qb + (size_t)myq * 128 + kq * 16 + half * 8);

    f32x16 oacc[4];                                  // O^T: row=d (4 tiles of 32), col=q
#pragma unroll
    for (int dt = 0; dt < 4; dt++)
#pragma unroll
        for (int c = 0; c < 16; c++) oacc[dt][c] = 0.0f;
    float m_s = -3e38f, l_s = 0.0f;

    const int rk = tid >> 4, xk = tid & 15, gk = xk ^ (rk & 15);  // sK: 16 chunks/row
    const int rv = tid >> 3, xv = tid & 7,  gv = xv ^ (rv & 7);   // sV: 8 chunks/row
    const int nkt = 2 * qt + 2;

    for (int kt = 0; kt < nkt; kt++) {
        const int kb0 = kt * 64;
#pragma unroll
        for (int i = 0; i < 4; i++) {
            async16(Kbh + (size_t)(kb0 + rk + i * 16) * 128 + gk * 8, sK + (i * 256 + tid) * 8);
            async16(Vbh + (size_t)(rv + i * 32) * 2048 + kb0 + gv * 8, sV + (i * 256 + tid) * 8);
        }
        __syncthreads();

        // S^T: rows = keys (2 tiles of 32), col = query
        f32x16 sacc[2];
#pragma unroll
        for (int t = 0; t < 2; t++)
#pragma unroll
            for (int c = 0; c < 16; c++) sacc[t][c] = 0.0f;
#pragma unroll
        for (int kq = 0; kq < 8; kq++) {
#pragma unroll
            for (int t = 0; t < 2; t++) {
                int row = t * 32 + l31;
                int x = (kq * 2 + half) ^ (row & 15);
                bf16x8 kf = *(const bf16x8*)(sK + row * 128 + x * 8);
                sacc[t] = MFMA32(kf, qf[kq], sacc[t]);
            }
        }

        // mask (key bias + causal); scale pre-folded into q
        float ps[2][16];
        float mx = -3e38f;
#pragma unroll
        for (int t = 0; t < 2; t++)
#pragma unroll
            for (int g = 0; g < 4; g++) {
                float4 mb4 = *(const float4*)(mbb + kb0 + t * 32 + 8 * g + 4 * half);
#pragma unroll
                for (int r2 = 0; r2 < 4; r2++) {
                    int sk = kb0 + t * 32 + 8 * g + 4 * half + r2;
                    float v = sacc[t][g * 4 + r2] + ((const float*)&mb4)[r2];
                    v = (sk > myq) ? -1e30f : v;
                    ps[t][g * 4 + r2] = v;
                    mx = fmaxf(mx, v);
                }
            }

        // online softmax: 32 in-lane values + 1 shuffle (partner lane^32 = same q)
        mx = fmaxf(mx, __shfl_xor(mx, 32, 64));
        float mnew  = fmaxf(m_s, mx);
        float alpha = __expf(m_s - mnew);
        float rs = 0.0f;
#pragma unroll
        for (int t = 0; t < 2; t++)
#pragma unroll
            for (int c = 0; c < 16; c++) {
                float p = __expf(ps[t][c] - mnew);
                ps[t][c] = p;
                rs += p;
            }
        rs += __shfl_xor(rs, 32, 64);
        l_s = l_s * alpha + rs;
        m_s = mnew;
#pragma unroll
        for (int dt = 0; dt < 4; dt++) oacc[dt] *= alpha;

        // write P to per-wave LDS [q][key], packed b64 (4 consecutive keys/reg-group)
#pragma unroll
        for (int t = 0; t < 2; t++)
#pragma unroll
            for (int g = 0; g < 4; g++) {
                int c = t * 4 + g;                 // key chunk = key>>3
                int x = c ^ (l31 & 7);
                bf16x4 p4;
#pragma unroll
                for (int r2 = 0; r2 < 4; r2++) p4[r2] = (bf16)ps[t][g * 4 + r2];
                *(bf16x4*)(sPw + l31 * 64 + x * 8 + half * 4) = p4;
            }

        // O^T += V^T P : A = vf (m=d), B = pf (n=q)
#pragma unroll
        for (int kq2 = 0; kq2 < 4; kq2++) {
            int cp = kq2 * 2 + half;
            int xp = cp ^ (l31 & 7);
            bf16x8 pf = *(const bf16x8*)(sPw + l31 * 64 + xp * 8);
#pragma unroll
            for (int dt = 0; dt < 4; dt++) {
                int row = dt * 32 + l31;
                int xv2 = cp ^ (row & 7);
                bf16x8 vf = *(const bf16x8*)(sV + row * 64 + xv2 * 8);
                oacc[dt] = MFMA32(vf, pf, oacc[dt]);
            }
        }
        __syncthreads();
    }

    // epilogue: lane = query myq; d = dt*32 + 8g + 4*half + r2; b64 stores
    float inv = 1.0f / l_s;
    size_t base = ((size_t)(b * 2048 + myq)) * 2048 + hh * 128;
#pragma unroll
    for (int dt = 0; dt < 4; dt++)
#pragma unroll
        for (int g = 0; g < 4; g++) {
            bf16x4 o4;
#pragma unroll
            for (int r2 = 0; r2 < 4; r2++) o4[r2] = (bf16)(oacc[dt][g * 4 + r2] * inv);
            *(bf16x4*)(O + base + dt * 32 + 8 * g + 4 * half) = o4;
        }
}

extern "C" void kernel_launch(void* const* d_in, const int* in_sizes, int n_in,
                              void* d_out, int out_size, void* d_ws, size_t ws_size,
                              hipStream_t stream) {
    const float* x     = (const float*)d_in[0];
    const int*   am    = (const int*)d_in[1];
    const float* qkvw  = (const float*)d_in[2];
    const float* qkvb  = (const float*)d_in[3];
    const float* outw  = (const float*)d_in[4];
    const float* outb  = (const float*)d_in[5];
    float* out = (float*)d_out;

    char* ws = (char*)d_ws;
    bf16*  xb    = (bf16*)(ws);                          // 16 MB  x bf16 [4096,2048]
    bf16*  wqkv  = (bf16*)(ws + (16ull << 20));          // 24 MB  qkv_w bf16 [6144,2048]
    bf16*  wout  = (bf16*)(ws + (40ull << 20));          //  8 MB  out_w bf16 [2048,2048]
    bf16*  qb    = (bf16*)(ws + (48ull << 20));          // 16 MB  q   [32, 2048, 128] (pre-scaled)
    bf16*  kb    = (bf16*)(ws + (64ull << 20));          // 16 MB  k   [32, 2048, 128]
    bf16*  vtb   = (bf16*)(ws + (80ull << 20));          // 16 MB  v^T [32, 128, 2048]
    bf16*  attn  = (bf16*)(ws + (96ull << 20));          // 16 MB  attn [4096, 2048]
    float* cosT  = (float*)(ws + (112ull << 20));        //  1 MB
    float* sinT  = (float*)(ws + (113ull << 20));        //  1 MB
    float* mbias = (float*)(ws + (114ull << 20));        // 16 KB

    cvt8<<<4096, 256, 0, stream>>>(x, xb, 4096 * 2048);
    cvt8<<<6144, 256, 0, stream>>>(qkvw, wqkv, 6144 * 2048);
    cvt8<<<2048, 256, 0, stream>>>(outw, wout, 2048 * 2048);
    tables_k<<<1024, 256, 0, stream>>>(am, cosT, sinT, mbias);

    gemm_bt<1><<<dim3(32, 48), 256, 0, stream>>>(
        xb, wqkv, qkvb, nullptr, qb, kb, vtb, cosT, sinT, 4096, 6144, 2048);

    fattn<<<dim3(16, 32), 256, 0, stream>>>(qb, kb, vtb, mbias, attn);

    gemm_bt<0><<<dim3(32, 16), 256, 0, stream>>>(
        attn, wout, outb, out, nullptr, nullptr, nullptr, nullptr, nullptr,
        4096, 2048, 2048);
}

// Round 5
// 409.003 us; speedup vs baseline: 1.1346x; 1.0108x over previous
//
#include <hip/hip_runtime.h>

typedef __bf16 bf16;
typedef __bf16 bf16x4 __attribute__((ext_vector_type(4)));
typedef __bf16 bf16x8 __attribute__((ext_vector_type(8)));
typedef float f32x4 __attribute__((ext_vector_type(4)));
typedef float f32x16 __attribute__((ext_vector_type(16)));

#define MFMA_BF16(a, b, c) __builtin_amdgcn_mfma_f32_16x16x32_bf16(a, b, c, 0, 0, 0)
#define MFMA32(a, b, c)    __builtin_amdgcn_mfma_f32_32x32x16_bf16(a, b, c, 0, 0, 0)

__device__ __forceinline__ void async16(const void* g, void* l) {
    __builtin_amdgcn_global_load_lds(
        (const __attribute__((address_space(1))) void*)g,
        (__attribute__((address_space(3))) void*)l,
        16, 0, 0);
}

// ---------------- fp32 -> bf16 convert, 8 elems/thread ----------------
__global__ void cvt8(const float* __restrict__ in, bf16* __restrict__ out, int n) {
    int i = (blockIdx.x * 256 + threadIdx.x) * 8;
    if (i >= n) return;
    float4 a = *(const float4*)(in + i);
    float4 b = *(const float4*)(in + i + 4);
    bf16x8 o;
    o[0] = (bf16)a.x; o[1] = (bf16)a.y; o[2] = (bf16)a.z; o[3] = (bf16)a.w;
    o[4] = (bf16)b.x; o[5] = (bf16)b.y; o[6] = (bf16)b.z; o[7] = (bf16)b.w;
    *(bf16x8*)(out + i) = o;
}

// ---------------- RoPE tables (S=2048, hd=128) + key-mask bias ----------------
__global__ void tables_k(const int* __restrict__ am, float* __restrict__ cosT,
                         float* __restrict__ sinT, float* __restrict__ mbias) {
    int i = blockIdx.x * 256 + threadIdx.x;   // 0 .. 2048*128-1
    int s = i >> 7, d = i & 127, fi = d & 63;
    float inv = exp2f(-(float)fi * (13.287712379549449f / 64.0f));
    float ang = (float)s * inv;
    cosT[i] = cosf(ang);
    sinT[i] = sinf(ang);
    if (i < 2 * 2048) mbias[i] = (am[i] == 0) ? -1e30f : 0.0f;
}

// ---------------- GEMM: C[M,N] = A[M,K] @ Bt[N,K]^T + bias ----------------
// 128x128 tile, BK=64, 4 waves (2x2). bn0 = column-tile offset (for split launches).
template <int EPI>
__global__ void __launch_bounds__(256, 2)
gemm_bt(const bf16* __restrict__ A, const bf16* __restrict__ Bt,
        const float* __restrict__ bias, float* __restrict__ Cf,
        bf16* __restrict__ qb, bf16* __restrict__ kb, bf16* __restrict__ vtb,
        const float* __restrict__ cosT, const float* __restrict__ sinT,
        int M, int N, int K, int bn0) {
    __shared__ __align__(16) bf16 sA[128 * 64];
    __shared__ __align__(16) bf16 sB[128 * 64];
    const int tid  = threadIdx.x;
    const int lane = tid & 63;
    const int quad = lane >> 4, l15 = lane & 15;
    const int wid = tid >> 6, wm = wid >> 1, wn = wid & 1;
    const int bm = blockIdx.x, bn = blockIdx.y + bn0;

    f32x4 acc[4][4];
#pragma unroll
    for (int i = 0; i < 4; i++)
#pragma unroll
        for (int j = 0; j < 4; j++)
#pragma unroll
            for (int c = 0; c < 4; c++) acc[i][j][c] = 0.0f;

    const int r0 = tid >> 3, x0 = tid & 7;
    const int g0 = x0 ^ (r0 & 7);
    const bf16* pa = A  + (size_t)(bm * 128 + r0) * K + g0 * 8;
    const bf16* pb = Bt + (size_t)(bn * 128 + r0) * K + g0 * 8;
    bf16* la = sA + tid * 8;
    bf16* lb = sB + tid * 8;
    const size_t gstep = (size_t)32 * K;

    for (int k0 = 0; k0 < K; k0 += 64) {
#pragma unroll
        for (int i = 0; i < 4; i++) {
            async16(pa + i * gstep, la + i * 2048);
            async16(pb + i * gstep, lb + i * 2048);
        }
        pa += 64; pb += 64;
        __syncthreads();
#pragma unroll
        for (int ks = 0; ks < 2; ks++) {
            bf16x8 af[4], bfr[4];
#pragma unroll
            for (int i = 0; i < 4; i++) {
                int r = wm * 64 + i * 16 + l15;
                int x = (ks * 4 + quad) ^ (r & 7);
                af[i] = *(const bf16x8*)(sA + r * 64 + x * 8);
            }
#pragma unroll
            for (int i = 0; i < 4; i++) {
                int r = wn * 64 + i * 16 + l15;
                int x = (ks * 4 + quad) ^ (r & 7);
                bfr[i] = *(const bf16x8*)(sB + r * 64 + x * 8);
            }
#pragma unroll
            for (int mi = 0; mi < 4; mi++)
#pragma unroll
                for (int ni = 0; ni < 4; ni++)
                    acc[mi][ni] = MFMA_BF16(af[mi], bfr[ni], acc[mi][ni]);
        }
        __syncthreads();
    }

    if (EPI == 0) {
#pragma unroll
        for (int mi = 0; mi < 4; mi++)
#pragma unroll
            for (int ni = 0; ni < 4; ni++) {
                int row0 = bm * 128 + wm * 64 + mi * 16 + quad * 4;
                int col  = bn * 128 + wn * 64 + ni * 16 + l15;
                float bv = bias[col];
#pragma unroll
                for (int r = 0; r < 4; r++)
                    Cf[(size_t)(row0 + r) * N + col] = acc[mi][ni][r] + bv;
            }
    } else {
#pragma unroll
        for (int mi = 0; mi < 4; mi++)
#pragma unroll
            for (int ni = 0; ni < 4; ni++) {
                int col   = bn * 128 + wn * 64 + ni * 16 + l15;
                int which = col >> 11;
                int hcol  = col & 2047;
                int h = hcol >> 7, d = hcol & 127;
                float bv = bias[col];
#pragma unroll
                for (int r = 0; r < 4; r++) {
                    int row = bm * 128 + wm * 64 + mi * 16 + quad * 4 + r;
                    int b = row >> 11, s = row & 2047;
                    float v  = acc[mi][ni][r] + bv;
                    float vp = __shfl_xor(v, 1, 64);   // partner column d^1
                    float ov = v;
                    if (which < 2) {
                        float c  = cosT[(s << 7) + d];
                        float sn = sinT[(s << 7) + d];
                        ov = v * c + ((d & 1) ? vp : -vp) * sn;
                    }
                    if (which == 0) ov *= 0.08838834764831845f;  // fold 1/sqrt(hd)
                    size_t bh = (size_t)(b * 16 + h);
                    if (which == 0)      qb[(bh * 2048 + s) * 128 + d] = (bf16)ov;
                    else if (which == 1) kb[(bh * 2048 + s) * 128 + d] = (bf16)ov;
                    else                 vtb[(bh * 128 + d) * 2048 + s] = (bf16)ov;
                }
            }
    }
}

// ---------------- Flash attention v4: 32x32x16, S^T/O^T, K/V double-buffered ----------------
// BM=128 (4 waves x 32 q), BN=64. Grid 16x32, 2 blocks/CU, LDS 80KB.
// Prefetch tile kt+1 into ping-pong buffer BEFORE computing tile kt; one barrier/iter.
// l_s kept as per-half partial; merged by one shuffle at the end.
__global__ void __launch_bounds__(256, 2)
fattn(const bf16* __restrict__ Q, const bf16* __restrict__ Kg,
      const bf16* __restrict__ Vt, const float* __restrict__ mbias,
      bf16* __restrict__ O) {
    __shared__ __align__(16) bf16 sK[2][64 * 128];   // [buf][key][d]
    __shared__ __align__(16) bf16 sV[2][128 * 64];   // [buf][d][key]
    __shared__ __align__(16) bf16 sP[4 * 32 * 64];   // per-wave [q][key]
    const int tid = threadIdx.x, lane = tid & 63, w = tid >> 6;
    const int l31 = lane & 31, half = lane >> 5;
    const int bx = (int)blockIdx.x;
    const int qt = (bx & 1) ? 15 - (bx >> 1) : (bx >> 1);  // work pairing
    const int bh = blockIdx.y, b = bh >> 4, hh = bh & 15;
    const int myq = qt * 128 + w * 32 + l31;

    const bf16* Qb  = Q  + (size_t)bh * 2048 * 128;
    const bf16* Kbh = Kg + (size_t)bh * 2048 * 128;
    const bf16* Vbh = Vt + (size_t)bh * 128 * 2048;
    const float* mbb = mbias + b * 2048;
    bf16* sPw = sP + w * 2048;

    // resident Q fragments: B-operand, n=query(l31), k = kq*16 + half*8 + j
    bf16x8 qf[8];
#pragma unroll
    for (int kq = 0; kq < 8; kq++)
        qf[kq] = *(const bf16x8*)(Qb + (size_t)myq * 128 + kq * 16 + half * 8);

    f32x16 oacc[4];
#pragma unroll
    for (int dt = 0; dt < 4; dt++)
#pragma unroll
        for (int c = 0; c < 16; c++) oacc[dt][c] = 0.0f;
    float m_s = -3e38f, l_s = 0.0f;   // l_s = partial sum over this half's keys

    const int rk = tid >> 4, xk = tid & 15, gk = xk ^ (rk & 15);  // sK: 16 chunks/row
    const int rv = tid >> 3, xv = tid & 7,  gv = xv ^ (rv & 7);   // sV: 8 chunks/row
    const int nkt = 2 * qt + 2;

    // stage tile 0 into buffer 0
#pragma unroll
    for (int i = 0; i < 4; i++) {
        async16(Kbh + (size_t)(rk + i * 16) * 128 + gk * 8, &sK[0][(i * 256 + tid) * 8]);
        async16(Vbh + (size_t)(rv + i * 32) * 2048 + gv * 8, &sV[0][(i * 256 + tid) * 8]);
    }
    __syncthreads();

    for (int kt = 0; kt < nkt; kt++) {
        const int kb0 = kt * 64;
        const int buf = kt & 1;
        // prefetch next tile into the other buffer (overlaps with compute below)
        if (kt + 1 < nkt) {
            const int nb0 = kb0 + 64;
#pragma unroll
            for (int i = 0; i < 4; i++) {
                async16(Kbh + (size_t)(nb0 + rk + i * 16) * 128 + gk * 8,
                        &sK[buf ^ 1][(i * 256 + tid) * 8]);
                async16(Vbh + (size_t)(rv + i * 32) * 2048 + nb0 + gv * 8,
                        &sV[buf ^ 1][(i * 256 + tid) * 8]);
            }
        }
        const bf16* sKb = sK[buf];
        const bf16* sVb = sV[buf];

        // S^T: rows = keys (2 tiles of 32), col = query
        f32x16 sacc[2];
#pragma unroll
        for (int t = 0; t < 2; t++)
#pragma unroll
            for (int c = 0; c < 16; c++) sacc[t][c] = 0.0f;
#pragma unroll
        for (int kq = 0; kq < 8; kq++) {
#pragma unroll
            for (int t = 0; t < 2; t++) {
                int row = t * 32 + l31;
                int x = (kq * 2 + half) ^ (row & 15);
                bf16x8 kf = *(const bf16x8*)(sKb + row * 128 + x * 8);
                sacc[t] = MFMA32(kf, qf[kq], sacc[t]);
            }
        }

        // mask (key bias + causal); scale pre-folded into q
        float ps[2][16];
        float mx = -3e38f;
#pragma unroll
        for (int t = 0; t < 2; t++)
#pragma unroll
            for (int g = 0; g < 4; g++) {
                float4 mb4 = *(const float4*)(mbb + kb0 + t * 32 + 8 * g + 4 * half);
#pragma unroll
                for (int r2 = 0; r2 < 4; r2++) {
                    int sk = kb0 + t * 32 + 8 * g + 4 * half + r2;
                    float v = sacc[t][g * 4 + r2] + ((const float*)&mb4)[r2];
                    v = (sk > myq) ? -1e30f : v;
                    ps[t][g * 4 + r2] = v;
                    mx = fmaxf(mx, v);
                }
            }

        // online softmax: 32 in-lane values + 1 cross-half shuffle for max only
        mx = fmaxf(mx, __shfl_xor(mx, 32, 64));
        float mnew  = fmaxf(m_s, mx);
        float alpha = __expf(m_s - mnew);
        float rs = 0.0f;
#pragma unroll
        for (int t = 0; t < 2; t++)
#pragma unroll
            for (int c = 0; c < 16; c++) {
                float p = __expf(ps[t][c] - mnew);
                ps[t][c] = p;
                rs += p;
            }
        l_s = l_s * alpha + rs;     // per-half partial; merged after the loop
        m_s = mnew;
#pragma unroll
        for (int dt = 0; dt < 4; dt++) oacc[dt] *= alpha;

        // write P to per-wave LDS [q][key], packed b64
#pragma unroll
        for (int t = 0; t < 2; t++)
#pragma unroll
            for (int g = 0; g < 4; g++) {
                int c = t * 4 + g;                 // key chunk = key>>3
                int x = c ^ (l31 & 7);
                bf16x4 p4;
#pragma unroll
                for (int r2 = 0; r2 < 4; r2++) p4[r2] = (bf16)ps[t][g * 4 + r2];
                *(bf16x4*)(sPw + l31 * 64 + x * 8 + half * 4) = p4;
            }

        // O^T += V^T P
#pragma unroll
        for (int kq2 = 0; kq2 < 4; kq2++) {
            int cp = kq2 * 2 + half;
            int xp = cp ^ (l31 & 7);
            bf16x8 pf = *(const bf16x8*)(sPw + l31 * 64 + xp * 8);
#pragma unroll
            for (int dt = 0; dt < 4; dt++) {
                int row = dt * 32 + l31;
                int xv2 = cp ^ (row & 7);
                bf16x8 vf = *(const bf16x8*)(sVb + row * 64 + xv2 * 8);
                oacc[dt] = MFMA32(vf, pf, oacc[dt]);
            }
        }
        // one barrier per iter: completes prefetch (vmcnt) AND retires all
        // reads of the current buffer before it is overwritten next iter.
        __syncthreads();
    }

    // merge per-half l, store O^T -> [b, s, h*128+d]
    l_s += __shfl_xor(l_s, 32, 64);
    float inv = 1.0f / l_s;
    size_t base = ((size_t)(b * 2048 + myq)) * 2048 + hh * 128;
#pragma unroll
    for (int dt = 0; dt < 4; dt++)
#pragma unroll
        for (int g = 0; g < 4; g++) {
            bf16x4 o4;
#pragma unroll
            for (int r2 = 0; r2 < 4; r2++) o4[r2] = (bf16)(oacc[dt][g * 4 + r2] * inv);
            *(bf16x4*)(O + base + dt * 32 + 8 * g + 4 * half) = o4;
        }
}

extern "C" void kernel_launch(void* const* d_in, const int* in_sizes, int n_in,
                              void* d_out, int out_size, void* d_ws, size_t ws_size,
                              hipStream_t stream) {
    const float* x     = (const float*)d_in[0];
    const int*   am    = (const int*)d_in[1];
    const float* qkvw  = (const float*)d_in[2];
    const float* qkvb  = (const float*)d_in[3];
    const float* outw  = (const float*)d_in[4];
    const float* outb  = (const float*)d_in[5];
    float* out = (float*)d_out;

    char* ws = (char*)d_ws;
    bf16*  xb    = (bf16*)(ws);                          // 16 MB  x bf16 [4096,2048]
    bf16*  wqkv  = (bf16*)(ws + (16ull << 20));          // 24 MB  qkv_w bf16 [6144,2048]
    bf16*  wout  = (bf16*)(ws + (40ull << 20));          //  8 MB  out_w bf16 [2048,2048]
    bf16*  qb    = (bf16*)(ws + (48ull << 20));          // 16 MB  q   [32, 2048, 128] (pre-scaled)
    bf16*  kb    = (bf16*)(ws + (64ull << 20));          // 16 MB  k   [32, 2048, 128]
    bf16*  vtb   = (bf16*)(ws + (80ull << 20));          // 16 MB  v^T [32, 128, 2048]
    bf16*  attn  = (bf16*)(ws + (96ull << 20));          // 16 MB  attn [4096, 2048]
    float* cosT  = (float*)(ws + (112ull << 20));        //  1 MB
    float* sinT  = (float*)(ws + (113ull << 20));        //  1 MB
    float* mbias = (float*)(ws + (114ull << 20));        // 16 KB

    cvt8<<<4096, 256, 0, stream>>>(x, xb, 4096 * 2048);
    cvt8<<<6144, 256, 0, stream>>>(qkvw, wqkv, 6144 * 2048);
    cvt8<<<2048, 256, 0, stream>>>(outw, wout, 2048 * 2048);
    tables_k<<<1024, 256, 0, stream>>>(am, cosT, sinT, mbias);

    // QKV GEMM split into two bn-halves (diagnostic: lets fattn surface in top-5)
    gemm_bt<1><<<dim3(32, 24), 256, 0, stream>>>(
        xb, wqkv, qkvb, nullptr, qb, kb, vtb, cosT, sinT, 4096, 6144, 2048, 0);
    gemm_bt<1><<<dim3(32, 24), 256, 0, stream>>>(
        xb, wqkv, qkvb, nullptr, qb, kb, vtb, cosT, sinT, 4096, 6144, 2048, 24);

    fattn<<<dim3(16, 32), 256, 0, stream>>>(qb, kb, vtb, mbias, attn);

    gemm_bt<0><<<dim3(32, 16), 256, 0, stream>>>(
        attn, wout, outb, out, nullptr, nullptr, nullptr, nullptr, nullptr,
        4096, 2048, 2048, 0);
}